// Round 1
// baseline (1966.213 us; speedup 1.0000x reference)
//
#include <hip/hip_runtime.h>
#include <math.h>

#define N_STEPS 50
#define DT 0.02f

// Two-hidden-layer MLP, input x[4], hidden 64/64, NOUT outputs.
// W1/W3/biases are wave-uniform s_loads (small, scalar-cache-resident now
// that W2 no longer streams through the K$). W2 comes from LDS via
// uniform-address ds_read_b128 (broadcast, conflict-free) -- this removes
// the 16 KB/step/wave scalar-load stream that thrashed the scalar cache
// and stalled all resident waves simultaneously.
// Layer1 stays fused into the layer2 row loop so acc[64] is only indexed
// by unrolled constants (no scratch).
template <int NOUT>
__device__ inline void mlp2(const float* __restrict__ W1, const float* __restrict__ b1,
                            const float* W2s,               // LDS, [64*64] row-major
                            const float* __restrict__ b2,
                            const float* __restrict__ W3, const float* __restrict__ b3,
                            float x0, float x1, float x2, float x3,
                            float* __restrict__ outv)
{
    float acc[64];
#pragma unroll
    for (int j = 0; j < 64; ++j) acc[j] = b2[j];

    // unroll 2: lets the scheduler hoist row i+1's ds_reads above row i's
    // fmas (cross-row LDS latency overlap) without blowing VGPRs.
#pragma unroll 2
    for (int i = 0; i < 64; ++i) {
        float h = b1[i];
        h = fmaf(x0, W1[i],        h);
        h = fmaf(x1, W1[64 + i],   h);
        h = fmaf(x2, W1[128 + i],  h);
        h = fmaf(x3, W1[192 + i],  h);
        h = fmaxf(h, 0.0f);
        const float* w2row = W2s + i * 64;
#pragma unroll
        for (int j = 0; j < 64; ++j) acc[j] = fmaf(h, w2row[j], acc[j]);
    }

#pragma unroll
    for (int c = 0; c < NOUT; ++c) outv[c] = b3[c];
#pragma unroll
    for (int j = 0; j < 64; ++j) {
        float hr = fmaxf(acc[j], 0.0f);
#pragma unroll
        for (int c = 0; c < NOUT; ++c) outv[c] = fmaf(hr, W3[j * NOUT + c], outv[c]);
    }
}

// Block = 256 threads = 4 waves, handles 128 paths.
//   wave 0: z-net for paths [base,     base+64)
//   wave 1: q-net for paths [base,     base+64)
//   wave 2: z-net for paths [base+64,  base+128)
//   wave 3: q-net for paths [base+64,  base+128)
// Net assignment is wave-granular so the remaining weight addresses stay
// wave-uniform (s_load). z<->q exchanged via double-buffered LDS,
// 1 barrier/step. Both waves of a pair integrate the identical y-state
// redundantly (bitwise-same f32 sequence), so no state exchange is needed.
__global__ __launch_bounds__(256) void bsde_kernel(
    const float* __restrict__ y0v, const float* __restrict__ Y0v,
    const float* __restrict__ qW1, const float* __restrict__ qb1,
    const float* __restrict__ qW2, const float* __restrict__ qb2,
    const float* __restrict__ qW3, const float* __restrict__ qb3,
    const float* __restrict__ zW1, const float* __restrict__ zb1,
    const float* __restrict__ zW2, const float* __restrict__ zb2,
    const float* __restrict__ zW3, const float* __restrict__ zb3,
    const float* __restrict__ dW,
    float* __restrict__ out, int B)
{
    const int lane = threadIdx.x & 63;
    const int wave = threadIdx.x >> 6;
    const int net  = wave & 1;            // 0 = z-net, 1 = q-net
    const int pair = wave >> 1;           // 0 or 1
    const int lp   = pair * 64 + lane;    // 0..127 within block
    const int p    = blockIdx.x * 128 + lp;

    __shared__ float sW2[2 * 4096];       // [net][64*64], z at 0, q at 4096
    __shared__ float zbuf[2][128][3];     // stride-3 floats: 2 lanes/bank, free
    __shared__ float qbuf[2][128];

    // Cooperative one-time W2 preload: 2048 float4s across 256 threads.
    {
        float4*       dst  = (float4*)sW2;
        const float4* zsrc = (const float4*)zW2;
        const float4* qsrc = (const float4*)qW2;
        for (int k = threadIdx.x; k < 1024; k += 256) {
            dst[k]        = zsrc[k];
            dst[1024 + k] = qsrc[k];
        }
    }
    __syncthreads();

    const float* W2s = sW2 + net * 4096;

    const float sqrt_dt = sqrtf(DT);

    float y0 = y0v[0], y1 = y0v[1], y2 = y0v[2];
    float Y  = Y0v[0];

    for (int n = 0; n < N_STEPS; ++n) {
        const float t  = (float)n * DT;
        const int   bu = n & 1;

        // Prefetch this step's dW BEFORE the MLP: its L2/L3 latency hides
        // under ~9.6k cycles of MLP compute instead of sitting on the
        // post-barrier critical path.
        const size_t idx = ((size_t)n * (size_t)B + (size_t)p) * 3;
        const float dr0 = dW[idx + 0];
        const float dr1 = dW[idx + 1];
        const float dr2 = dW[idx + 2];

        if (net == 0) {
            float z[3];
            mlp2<3>(zW1, zb1, W2s, zb2, zW3, zb3, t, y0, y1, y2, z);
            zbuf[bu][lp][0] = z[0];
            zbuf[bu][lp][1] = z[1];
            zbuf[bu][lp][2] = z[2];
        } else {
            float q[1];
            mlp2<1>(qW1, qb1, W2s, qb2, qW3, qb3, t, y0, y1, y2, q);
            qbuf[bu][lp] = q[0];
        }
        __syncthreads();

        const float qq = qbuf[bu][lp];
        const float z0 = zbuf[bu][lp][0];
        const float z1 = zbuf[bu][lp][1];
        const float z2 = zbuf[bu][lp][2];
        const float f  = 0.5f * qq * qq;

        const float dw0 = dr0 * sqrt_dt;
        const float dw1 = dr1 * sqrt_dt;
        const float dw2 = dr2 * sqrt_dt;

        Y = Y - f * DT + (z0 * dw0 + z1 * dw1 + z2 * dw2);

        const float s0 = 0.2f + 0.1f * tanhf(y0);
        const float s1 = 0.2f + 0.1f * tanhf(y1);
        const float s2 = 0.2f + 0.1f * tanhf(y2);
        y0 = y0 + (qq - y0) * DT + s0 * dw0;
        y1 = y1 + (qq - y1) * DT + s1 * dw1;
        y2 = y2 + (qq - y2) * DT + s2 * dw2;
    }

    // Only the z-waves contribute each path once.
    if (net == 0) {
        const float term = y0 * y0 + y1 * y1 + y2 * y2;
        const float d    = Y - term;
        float val = d * d;
#pragma unroll
        for (int off = 32; off > 0; off >>= 1)
            val += __shfl_down(val, off, 64);
        if (lane == 0)
            atomicAdd(out, val * (1.0f / (float)B));
    }
}

extern "C" void kernel_launch(void* const* d_in, const int* in_sizes, int n_in,
                              void* d_out, int out_size, void* d_ws, size_t ws_size,
                              hipStream_t stream) {
    const float* y0  = (const float*)d_in[0];
    const float* Y0  = (const float*)d_in[1];
    const float* qW1 = (const float*)d_in[2];
    const float* qb1 = (const float*)d_in[3];
    const float* qW2 = (const float*)d_in[4];
    const float* qb2 = (const float*)d_in[5];
    const float* qW3 = (const float*)d_in[6];
    const float* qb3 = (const float*)d_in[7];
    const float* zW1 = (const float*)d_in[8];
    const float* zb1 = (const float*)d_in[9];
    const float* zW2 = (const float*)d_in[10];
    const float* zb2 = (const float*)d_in[11];
    const float* zW3 = (const float*)d_in[12];
    const float* zb3 = (const float*)d_in[13];
    const float* dW  = (const float*)d_in[14];

    const int B = in_sizes[14] / (N_STEPS * 3);   // 131072
    float* out = (float*)d_out;

    hipMemsetAsync(out, 0, sizeof(float), stream);

    const int threads = 256;                       // 4 waves: 2 path-groups x 2 nets
    const int blocks  = B / 128;                   // 1024 blocks
    bsde_kernel<<<blocks, threads, 0, stream>>>(
        y0, Y0, qW1, qb1, qW2, qb2, qW3, qb3,
        zW1, zb1, zW2, zb2, zW3, zb3, dW, out, B);
}

// Round 2
// 1443.989 us; speedup vs baseline: 1.3617x; 1.3617x over previous
//
#include <hip/hip_runtime.h>
#include <math.h>

#define N_STEPS 50
#define DT 0.02f

// Two-hidden-layer MLP, input x[4], hidden 64/64, NOUT outputs, evaluated
// for TWO paths (A, B) per thread sharing one weight stream.
// Weights are wave-uniform -> all weight reads are s_loads (SGPR operand
// to v_fmac: zero VALU slots, zero VGPRs). Processing 2 paths per thread
// halves scalar-cache miss traffic per FLOP and doubles the independent
// FMA work covering each W2-row load's latency (128 fma vs ~200 cyc).
// Layer1 is fused into the row loop; acc arrays are only indexed by
// unrolled constants (no scratch). Per-path fma order is bitwise identical
// to the 1-path version.
template <int NOUT>
__device__ inline void mlp2_x2(const float* __restrict__ W1, const float* __restrict__ b1,
                               const float* __restrict__ W2, const float* __restrict__ b2,
                               const float* __restrict__ W3, const float* __restrict__ b3,
                               float t,
                               float a0, float a1, float a2,     // path A state
                               float c0, float c1, float c2,     // path B state
                               float* __restrict__ outA, float* __restrict__ outB)
{
    float accA[64], accB[64];
#pragma unroll
    for (int j = 0; j < 64; ++j) {
        const float b = b2[j];
        accA[j] = b;
        accB[j] = b;
    }

    // unroll 2: lets the scheduler issue row i+1's s_loads during row i's
    // 128-fma stretch (cross-row latency overlap).
#pragma unroll 2
    for (int i = 0; i < 64; ++i) {
        const float w0 = W1[i];
        const float w1 = W1[64 + i];
        const float w2 = W1[128 + i];
        const float w3 = W1[192 + i];
        const float bb = b1[i];

        float hA = bb;
        hA = fmaf(t,  w0, hA);
        hA = fmaf(a0, w1, hA);
        hA = fmaf(a1, w2, hA);
        hA = fmaf(a2, w3, hA);
        hA = fmaxf(hA, 0.0f);

        float hB = bb;
        hB = fmaf(t,  w0, hB);
        hB = fmaf(c0, w1, hB);
        hB = fmaf(c1, w2, hB);
        hB = fmaf(c2, w3, hB);
        hB = fmaxf(hB, 0.0f);

        const float* __restrict__ w2row = W2 + i * 64;
#pragma unroll
        for (int j = 0; j < 64; ++j) {
            const float w = w2row[j];
            accA[j] = fmaf(hA, w, accA[j]);
            accB[j] = fmaf(hB, w, accB[j]);
        }
    }

#pragma unroll
    for (int c = 0; c < NOUT; ++c) { outA[c] = b3[c]; outB[c] = b3[c]; }
#pragma unroll
    for (int j = 0; j < 64; ++j) {
        const float hrA = fmaxf(accA[j], 0.0f);
        const float hrB = fmaxf(accB[j], 0.0f);
#pragma unroll
        for (int c = 0; c < NOUT; ++c) {
            const float w = W3[j * NOUT + c];
            outA[c] = fmaf(hrA, w, outA[c]);
            outB[c] = fmaf(hrB, w, outB[c]);
        }
    }
}

// Block = 256 threads = 4 waves, handles 256 paths (2 per thread).
//   wave 0: z-net for paths [base,      base+128)
//   wave 1: q-net for paths [base,      base+128)
//   wave 2: z-net for paths [base+128,  base+256)
//   wave 3: q-net for paths [base+128,  base+256)
// Net assignment is wave-granular so weight addresses stay wave-uniform
// (s_load). z<->q exchanged via double-buffered LDS, 1 barrier/step. Both
// waves of a pair integrate the identical y-state redundantly (bitwise-same
// f32 sequence), so no state exchange is needed.
__global__ __launch_bounds__(256) void bsde_kernel(
    const float* __restrict__ y0v, const float* __restrict__ Y0v,
    const float* __restrict__ qW1, const float* __restrict__ qb1,
    const float* __restrict__ qW2, const float* __restrict__ qb2,
    const float* __restrict__ qW3, const float* __restrict__ qb3,
    const float* __restrict__ zW1, const float* __restrict__ zb1,
    const float* __restrict__ zW2, const float* __restrict__ zb2,
    const float* __restrict__ zW3, const float* __restrict__ zb3,
    const float* __restrict__ dW,
    float* __restrict__ out, int B)
{
    const int lane = threadIdx.x & 63;
    const int wave = threadIdx.x >> 6;
    const int net  = wave & 1;            // 0 = z-net, 1 = q-net
    const int pair = wave >> 1;           // 0 or 1
    const int lpA  = pair * 128 + lane;   // 0..255 within block
    const int lpB  = lpA + 64;
    const int pA   = blockIdx.x * 256 + lpA;
    const int pB   = pA + 64;

    __shared__ float zbuf[2][256][3];     // stride-3 floats: conflict-free
    __shared__ float qbuf[2][256];

    const float sqrt_dt = sqrtf(DT);

    float yA0 = y0v[0], yA1 = y0v[1], yA2 = y0v[2];
    float yB0 = yA0,    yB1 = yA1,    yB2 = yA2;
    float YA  = Y0v[0];
    float YB  = YA;

    for (int n = 0; n < N_STEPS; ++n) {
        const float t  = (float)n * DT;
        const int   bu = n & 1;

        // Prefetch this step's dW BEFORE the MLP: its L2/L3 latency hides
        // under ~19k cycles of MLP compute instead of sitting on the
        // post-barrier critical path.
        const size_t idxA = ((size_t)n * (size_t)B + (size_t)pA) * 3;
        const size_t idxB = ((size_t)n * (size_t)B + (size_t)pB) * 3;
        const float drA0 = dW[idxA + 0];
        const float drA1 = dW[idxA + 1];
        const float drA2 = dW[idxA + 2];
        const float drB0 = dW[idxB + 0];
        const float drB1 = dW[idxB + 1];
        const float drB2 = dW[idxB + 2];

        if (net == 0) {
            float zA[3], zB[3];
            mlp2_x2<3>(zW1, zb1, zW2, zb2, zW3, zb3, t,
                       yA0, yA1, yA2, yB0, yB1, yB2, zA, zB);
            zbuf[bu][lpA][0] = zA[0];
            zbuf[bu][lpA][1] = zA[1];
            zbuf[bu][lpA][2] = zA[2];
            zbuf[bu][lpB][0] = zB[0];
            zbuf[bu][lpB][1] = zB[1];
            zbuf[bu][lpB][2] = zB[2];
        } else {
            float qA[1], qB[1];
            mlp2_x2<1>(qW1, qb1, qW2, qb2, qW3, qb3, t,
                       yA0, yA1, yA2, yB0, yB1, yB2, qA, qB);
            qbuf[bu][lpA] = qA[0];
            qbuf[bu][lpB] = qB[0];
        }
        __syncthreads();

        const float qqA = qbuf[bu][lpA];
        const float zA0 = zbuf[bu][lpA][0];
        const float zA1 = zbuf[bu][lpA][1];
        const float zA2 = zbuf[bu][lpA][2];
        const float qqB = qbuf[bu][lpB];
        const float zB0 = zbuf[bu][lpB][0];
        const float zB1 = zbuf[bu][lpB][1];
        const float zB2 = zbuf[bu][lpB][2];

        const float fA = 0.5f * qqA * qqA;
        const float fB = 0.5f * qqB * qqB;

        const float dwA0 = drA0 * sqrt_dt;
        const float dwA1 = drA1 * sqrt_dt;
        const float dwA2 = drA2 * sqrt_dt;
        const float dwB0 = drB0 * sqrt_dt;
        const float dwB1 = drB1 * sqrt_dt;
        const float dwB2 = drB2 * sqrt_dt;

        YA = YA - fA * DT + (zA0 * dwA0 + zA1 * dwA1 + zA2 * dwA2);
        YB = YB - fB * DT + (zB0 * dwB0 + zB1 * dwB1 + zB2 * dwB2);

        const float sA0 = 0.2f + 0.1f * tanhf(yA0);
        const float sA1 = 0.2f + 0.1f * tanhf(yA1);
        const float sA2 = 0.2f + 0.1f * tanhf(yA2);
        yA0 = yA0 + (qqA - yA0) * DT + sA0 * dwA0;
        yA1 = yA1 + (qqA - yA1) * DT + sA1 * dwA1;
        yA2 = yA2 + (qqA - yA2) * DT + sA2 * dwA2;

        const float sB0 = 0.2f + 0.1f * tanhf(yB0);
        const float sB1 = 0.2f + 0.1f * tanhf(yB1);
        const float sB2 = 0.2f + 0.1f * tanhf(yB2);
        yB0 = yB0 + (qqB - yB0) * DT + sB0 * dwB0;
        yB1 = yB1 + (qqB - yB1) * DT + sB1 * dwB1;
        yB2 = yB2 + (qqB - yB2) * DT + sB2 * dwB2;
    }

    // Only the z-waves contribute; each path counted once.
    if (net == 0) {
        const float termA = yA0 * yA0 + yA1 * yA1 + yA2 * yA2;
        const float termB = yB0 * yB0 + yB1 * yB1 + yB2 * yB2;
        const float dA = YA - termA;
        const float dB = YB - termB;
        float val = dA * dA + dB * dB;
#pragma unroll
        for (int off = 32; off > 0; off >>= 1)
            val += __shfl_down(val, off, 64);
        if (lane == 0)
            atomicAdd(out, val * (1.0f / (float)B));
    }
}

extern "C" void kernel_launch(void* const* d_in, const int* in_sizes, int n_in,
                              void* d_out, int out_size, void* d_ws, size_t ws_size,
                              hipStream_t stream) {
    const float* y0  = (const float*)d_in[0];
    const float* Y0  = (const float*)d_in[1];
    const float* qW1 = (const float*)d_in[2];
    const float* qb1 = (const float*)d_in[3];
    const float* qW2 = (const float*)d_in[4];
    const float* qb2 = (const float*)d_in[5];
    const float* qW3 = (const float*)d_in[6];
    const float* qb3 = (const float*)d_in[7];
    const float* zW1 = (const float*)d_in[8];
    const float* zb1 = (const float*)d_in[9];
    const float* zW2 = (const float*)d_in[10];
    const float* zb2 = (const float*)d_in[11];
    const float* zW3 = (const float*)d_in[12];
    const float* zb3 = (const float*)d_in[13];
    const float* dW  = (const float*)d_in[14];

    const int B = in_sizes[14] / (N_STEPS * 3);   // 131072
    float* out = (float*)d_out;

    hipMemsetAsync(out, 0, sizeof(float), stream);

    const int threads = 256;                       // 4 waves: 2 path-groups x 2 nets
    const int blocks  = B / 256;                   // 512 blocks
    bsde_kernel<<<blocks, threads, 0, stream>>>(
        y0, Y0, qW1, qb1, qW2, qb2, qW3, qb3,
        zW1, zb1, zW2, zb2, zW3, zb3, dW, out, B);
}

// Round 3
// 1434.527 us; speedup vs baseline: 1.3706x; 1.0066x over previous
//
#include <hip/hip_runtime.h>
#include <math.h>

#define N_STEPS 50
#define DT 0.02f

typedef float v2f __attribute__((ext_vector_type(2)));

// Two-hidden-layer MLP, input x[4], hidden 64/64, NOUT outputs, evaluated
// for TWO paths (A, B) per thread sharing one weight stream.
//
// Key change vs round 2: the dominant W2 inner loop now uses PACKED fp32
// (v_pk_fma_f32 via <2 x float> llvm.fma) -- 2 FLOPs/lane/instr, the only
// way to reach MI355X's full fp32 rate. Packing is along the j (output)
// dimension: acc2[k] += h_splat * w_pair[k], where w_pair is an aligned
// SGPR pair straight from the uniform s_load stream. Each acc[j] keeps
// exactly the same fma sequence as the scalar version (independent
// accumulator chains, same order) -> per-path arithmetic stays bitwise
// identical. Layer 1 and the output layer remain scalar-sequential for
// the same reason.
template <int NOUT>
__device__ inline void mlp2_x2(const float* __restrict__ W1, const float* __restrict__ b1,
                               const float* __restrict__ W2, const float* __restrict__ b2,
                               const float* __restrict__ W3, const float* __restrict__ b3,
                               float t,
                               float a0, float a1, float a2,     // path A state
                               float c0, float c1, float c2,     // path B state
                               float* __restrict__ outA, float* __restrict__ outB)
{
    v2f accA[32], accB[32];
    const v2f* __restrict__ b2v = (const v2f*)b2;
#pragma unroll
    for (int k = 0; k < 32; ++k) {
        const v2f b = b2v[k];
        accA[k] = b;
        accB[k] = b;
    }

    // unroll 2: lets the scheduler issue row i+1's s_loads during row i's
    // pk_fma stretch (cross-row latency overlap).
#pragma unroll 2
    for (int i = 0; i < 64; ++i) {
        const float w0 = W1[i];
        const float w1 = W1[64 + i];
        const float w2 = W1[128 + i];
        const float w3 = W1[192 + i];
        const float bb = b1[i];

        float hA = bb;
        hA = fmaf(t,  w0, hA);
        hA = fmaf(a0, w1, hA);
        hA = fmaf(a1, w2, hA);
        hA = fmaf(a2, w3, hA);
        hA = fmaxf(hA, 0.0f);

        float hB = bb;
        hB = fmaf(t,  w0, hB);
        hB = fmaf(c0, w1, hB);
        hB = fmaf(c1, w2, hB);
        hB = fmaf(c2, w3, hB);
        hB = fmaxf(hB, 0.0f);

        const v2f hA2 = {hA, hA};
        const v2f hB2 = {hB, hB};

        const v2f* __restrict__ w2row = (const v2f*)(W2 + i * 64);
#pragma unroll
        for (int k = 0; k < 32; ++k) {
            const v2f w = w2row[k];
            accA[k] = __builtin_elementwise_fma(hA2, w, accA[k]);
            accB[k] = __builtin_elementwise_fma(hB2, w, accB[k]);
        }
    }

    // Output layer: scalar, strictly sequential in j -- bitwise identical
    // to all previous rounds. ~10% of instructions; not worth reordering.
#pragma unroll
    for (int c = 0; c < NOUT; ++c) { outA[c] = b3[c]; outB[c] = b3[c]; }
#pragma unroll
    for (int k = 0; k < 32; ++k) {
        const float hrA0 = fmaxf(accA[k].x, 0.0f);
        const float hrA1 = fmaxf(accA[k].y, 0.0f);
        const float hrB0 = fmaxf(accB[k].x, 0.0f);
        const float hrB1 = fmaxf(accB[k].y, 0.0f);
#pragma unroll
        for (int c = 0; c < NOUT; ++c) {
            const float we = W3[(2 * k) * NOUT + c];
            const float wo = W3[(2 * k + 1) * NOUT + c];
            outA[c] = fmaf(hrA0, we, outA[c]);
            outB[c] = fmaf(hrB0, we, outB[c]);
            outA[c] = fmaf(hrA1, wo, outA[c]);
            outB[c] = fmaf(hrB1, wo, outB[c]);
        }
    }
}

// Block = 256 threads = 4 waves, handles 256 paths (2 per thread).
//   wave 0: z-net for paths [base,      base+128)
//   wave 1: q-net for paths [base,      base+128)
//   wave 2: z-net for paths [base+128,  base+256)
//   wave 3: q-net for paths [base+128,  base+256)
// Net assignment is wave-granular so weight addresses stay wave-uniform
// (s_load). z<->q exchanged via double-buffered LDS, 1 barrier/step. Both
// waves of a pair integrate the identical y-state redundantly (bitwise-same
// f32 sequence), so no state exchange is needed.
// launch_bounds(256,2): cap VGPRs at 256 so both blocks stay resident
// (2 waves/SIMD) despite the 128-VGPR accumulator arrays.
__global__ __launch_bounds__(256, 2) void bsde_kernel(
    const float* __restrict__ y0v, const float* __restrict__ Y0v,
    const float* __restrict__ qW1, const float* __restrict__ qb1,
    const float* __restrict__ qW2, const float* __restrict__ qb2,
    const float* __restrict__ qW3, const float* __restrict__ qb3,
    const float* __restrict__ zW1, const float* __restrict__ zb1,
    const float* __restrict__ zW2, const float* __restrict__ zb2,
    const float* __restrict__ zW3, const float* __restrict__ zb3,
    const float* __restrict__ dW,
    float* __restrict__ out, int B)
{
    const int lane = threadIdx.x & 63;
    const int wave = threadIdx.x >> 6;
    const int net  = wave & 1;            // 0 = z-net, 1 = q-net
    const int pair = wave >> 1;           // 0 or 1
    const int lpA  = pair * 128 + lane;   // 0..255 within block
    const int lpB  = lpA + 64;
    const int pA   = blockIdx.x * 256 + lpA;
    const int pB   = pA + 64;

    __shared__ float zbuf[2][256][3];     // stride-3 floats: conflict-free
    __shared__ float qbuf[2][256];

    const float sqrt_dt = sqrtf(DT);

    float yA0 = y0v[0], yA1 = y0v[1], yA2 = y0v[2];
    float yB0 = yA0,    yB1 = yA1,    yB2 = yA2;
    float YA  = Y0v[0];
    float YB  = YA;

    for (int n = 0; n < N_STEPS; ++n) {
        const float t  = (float)n * DT;
        const int   bu = n & 1;

        // Prefetch this step's dW BEFORE the MLP: its L2/L3 latency hides
        // under the MLP compute instead of sitting on the post-barrier
        // critical path.
        const size_t idxA = ((size_t)n * (size_t)B + (size_t)pA) * 3;
        const size_t idxB = ((size_t)n * (size_t)B + (size_t)pB) * 3;
        const float drA0 = dW[idxA + 0];
        const float drA1 = dW[idxA + 1];
        const float drA2 = dW[idxA + 2];
        const float drB0 = dW[idxB + 0];
        const float drB1 = dW[idxB + 1];
        const float drB2 = dW[idxB + 2];

        if (net == 0) {
            float zA[3], zB[3];
            mlp2_x2<3>(zW1, zb1, zW2, zb2, zW3, zb3, t,
                       yA0, yA1, yA2, yB0, yB1, yB2, zA, zB);
            zbuf[bu][lpA][0] = zA[0];
            zbuf[bu][lpA][1] = zA[1];
            zbuf[bu][lpA][2] = zA[2];
            zbuf[bu][lpB][0] = zB[0];
            zbuf[bu][lpB][1] = zB[1];
            zbuf[bu][lpB][2] = zB[2];
        } else {
            float qA[1], qB[1];
            mlp2_x2<1>(qW1, qb1, qW2, qb2, qW3, qb3, t,
                       yA0, yA1, yA2, yB0, yB1, yB2, qA, qB);
            qbuf[bu][lpA] = qA[0];
            qbuf[bu][lpB] = qB[0];
        }
        __syncthreads();

        const float qqA = qbuf[bu][lpA];
        const float zA0 = zbuf[bu][lpA][0];
        const float zA1 = zbuf[bu][lpA][1];
        const float zA2 = zbuf[bu][lpA][2];
        const float qqB = qbuf[bu][lpB];
        const float zB0 = zbuf[bu][lpB][0];
        const float zB1 = zbuf[bu][lpB][1];
        const float zB2 = zbuf[bu][lpB][2];

        const float fA = 0.5f * qqA * qqA;
        const float fB = 0.5f * qqB * qqB;

        const float dwA0 = drA0 * sqrt_dt;
        const float dwA1 = drA1 * sqrt_dt;
        const float dwA2 = drA2 * sqrt_dt;
        const float dwB0 = drB0 * sqrt_dt;
        const float dwB1 = drB1 * sqrt_dt;
        const float dwB2 = drB2 * sqrt_dt;

        YA = YA - fA * DT + (zA0 * dwA0 + zA1 * dwA1 + zA2 * dwA2);
        YB = YB - fB * DT + (zB0 * dwB0 + zB1 * dwB1 + zB2 * dwB2);

        const float sA0 = 0.2f + 0.1f * tanhf(yA0);
        const float sA1 = 0.2f + 0.1f * tanhf(yA1);
        const float sA2 = 0.2f + 0.1f * tanhf(yA2);
        yA0 = yA0 + (qqA - yA0) * DT + sA0 * dwA0;
        yA1 = yA1 + (qqA - yA1) * DT + sA1 * dwA1;
        yA2 = yA2 + (qqA - yA2) * DT + sA2 * dwA2;

        const float sB0 = 0.2f + 0.1f * tanhf(yB0);
        const float sB1 = 0.2f + 0.1f * tanhf(yB1);
        const float sB2 = 0.2f + 0.1f * tanhf(yB2);
        yB0 = yB0 + (qqB - yB0) * DT + sB0 * dwB0;
        yB1 = yB1 + (qqB - yB1) * DT + sB1 * dwB1;
        yB2 = yB2 + (qqB - yB2) * DT + sB2 * dwB2;
    }

    // Only the z-waves contribute; each path counted once.
    if (net == 0) {
        const float termA = yA0 * yA0 + yA1 * yA1 + yA2 * yA2;
        const float termB = yB0 * yB0 + yB1 * yB1 + yB2 * yB2;
        const float dA = YA - termA;
        const float dB = YB - termB;
        float val = dA * dA + dB * dB;
#pragma unroll
        for (int off = 32; off > 0; off >>= 1)
            val += __shfl_down(val, off, 64);
        if (lane == 0)
            atomicAdd(out, val * (1.0f / (float)B));
    }
}

extern "C" void kernel_launch(void* const* d_in, const int* in_sizes, int n_in,
                              void* d_out, int out_size, void* d_ws, size_t ws_size,
                              hipStream_t stream) {
    const float* y0  = (const float*)d_in[0];
    const float* Y0  = (const float*)d_in[1];
    const float* qW1 = (const float*)d_in[2];
    const float* qb1 = (const float*)d_in[3];
    const float* qW2 = (const float*)d_in[4];
    const float* qb2 = (const float*)d_in[5];
    const float* qW3 = (const float*)d_in[6];
    const float* qb3 = (const float*)d_in[7];
    const float* zW1 = (const float*)d_in[8];
    const float* zb1 = (const float*)d_in[9];
    const float* zW2 = (const float*)d_in[10];
    const float* zb2 = (const float*)d_in[11];
    const float* zW3 = (const float*)d_in[12];
    const float* zb3 = (const float*)d_in[13];
    const float* dW  = (const float*)d_in[14];

    const int B = in_sizes[14] / (N_STEPS * 3);   // 131072
    float* out = (float*)d_out;

    hipMemsetAsync(out, 0, sizeof(float), stream);

    const int threads = 256;                       // 4 waves: 2 path-groups x 2 nets
    const int blocks  = B / 256;                   // 512 blocks
    bsde_kernel<<<blocks, threads, 0, stream>>>(
        y0, Y0, qW1, qb1, qW2, qb2, qW3, qb3,
        zW1, zb1, zW2, zb2, zW3, zb3, dW, out, B);
}